// Round 1
// baseline (2466.212 us; speedup 1.0000x reference)
//
#include <hip/hip_runtime.h>
#include <cstdint>
#include <cstddef>

// SplineNet: 2x SplineConv (K=3, K=5; dim=1, degree=1, mean aggr, root+bias)
// + ELU, then fused MLP head (D->D relu, D->C relu).
// N=100000, E=1600000, D=64, C=16.
//
// Strategy:
//  - scatter_k: one wave per edge; lane=feature. Each edge adds
//    (1-frac)*x[src] into agg[dst][i0] and frac*x[src] into agg[dst][i1]
//    via hardware fp32 atomics (unsafeAtomicAdd -> global_atomic_add_f32).
//    deg histogram (int atomics) folded into the first scatter.
//  - conv_out_k: one wave per node; lane=output col. out = (agg_row @ Wcat)/max(deg,1)
//    + x_row @ root + bias, then ELU. agg row reads are wave-broadcast (cache hits);
//    W reads coalesced and L2-resident.
//  - mlp_fused: one wave per node. hidden h[lane] = relu(h2row@Wm1+bm1);
//    second layer via shuffles: lane(part,c) partial sums + xor-reduce, lanes<16 store.
//
// Workspace layout (floats): agg[N*5*64] | h1[N*64] | h2[N*64] | deg[N] (uint)
//   = 128MB + 25.6MB + 25.6MB + 0.4MB ~= 180MB.

#define D_FEAT 64

__device__ __forceinline__ float elu_f(float x) {
    return x > 0.f ? x : expm1f(x);
}

template<int K, bool DO_DEG>
__global__ __launch_bounds__(256) void scatter_k(
    const float* __restrict__ xin,
    const int* __restrict__ esrc,
    const int* __restrict__ edst,
    const float* __restrict__ attr,
    float* __restrict__ agg,
    unsigned int* __restrict__ deg,
    int E)
{
    int w = blockIdx.x * (blockDim.x >> 6) + (threadIdx.x >> 6);
    int lane = threadIdx.x & 63;
    if (w >= E) return;
    int s = esrc[w];
    int d = edst[w];
    float p = attr[w];
    float v = p * (float)(K - 1);
    float fv = floorf(v);
    int i0 = (int)fv;
    i0 = i0 < 0 ? 0 : (i0 > K - 1 ? K - 1 : i0);
    int i1 = (i0 + 1 > K - 1) ? K - 1 : i0 + 1;
    float frac = v - fv;
    float xv = xin[(size_t)s * D_FEAT + lane];
    float* base = agg + ((size_t)d * K) * D_FEAT + lane;
    unsafeAtomicAdd(base + i0 * D_FEAT, xv * (1.f - frac));
    unsafeAtomicAdd(base + i1 * D_FEAT, xv * frac);
    if (DO_DEG && lane == 0) atomicAdd(deg + d, 1u);
}

template<int K>
__global__ __launch_bounds__(256) void conv_out_k(
    const float* __restrict__ agg,
    const float* __restrict__ xin,
    const float* __restrict__ W,      // [K*64, 64] (i.e. [K][D][D] row-major)
    const float* __restrict__ root,   // [64, 64]
    const float* __restrict__ bias,   // [64]
    const unsigned int* __restrict__ deg,
    float* __restrict__ out,
    int N)
{
    int n = blockIdx.x * (blockDim.x >> 6) + (threadIdx.x >> 6);
    int lane = threadIdx.x & 63;
    if (n >= N) return;
    const float* arow = agg + (size_t)n * (K * D_FEAT);
    float acc = 0.f;
    #pragma unroll 8
    for (int i = 0; i < K * D_FEAT; ++i)
        acc = fmaf(arow[i], W[i * D_FEAT + lane], acc);
    float dn = (float)deg[n];
    acc /= fmaxf(dn, 1.f);
    const float* xrow = xin + (size_t)n * D_FEAT;
    float acc2 = 0.f;
    #pragma unroll 8
    for (int d = 0; d < D_FEAT; ++d)
        acc2 = fmaf(xrow[d], root[d * D_FEAT + lane], acc2);
    float r = acc + acc2 + bias[lane];
    out[(size_t)n * D_FEAT + lane] = elu_f(r);
}

__global__ __launch_bounds__(256) void mlp_fused(
    const float* __restrict__ hin,    // [N, 64]
    const float* __restrict__ Wm1,    // [64, 64]
    const float* __restrict__ bm1,    // [64]
    const float* __restrict__ Wm2,    // [64, 16]
    const float* __restrict__ bm2,    // [16]
    float* __restrict__ out,          // [N, 16]
    int N)
{
    int n = blockIdx.x * (blockDim.x >> 6) + (threadIdx.x >> 6);
    int lane = threadIdx.x & 63;
    if (n >= N) return;
    const float* hrow = hin + (size_t)n * D_FEAT;
    float a = 0.f;
    #pragma unroll 8
    for (int d = 0; d < D_FEAT; ++d)
        a = fmaf(hrow[d], Wm1[d * D_FEAT + lane], a);
    float h = fmaxf(a + bm1[lane], 0.f);   // relu(h @ Wm1 + bm1), lane holds col

    // second layer: out[c] = relu(sum_d h[d]*Wm2[d*16+c] + bm2[c])
    int c = lane & 15;
    int part = lane >> 4;
    float p = 0.f;
    #pragma unroll
    for (int j = 0; j < 16; ++j) {
        int d = part * 16 + j;
        float hd = __shfl(h, d);
        p = fmaf(hd, Wm2[d * 16 + c], p);
    }
    p += __shfl_xor(p, 16);
    p += __shfl_xor(p, 32);
    if (lane < 16)
        out[(size_t)n * 16 + lane] = fmaxf(p + bm2[lane], 0.f);
}

extern "C" void kernel_launch(void* const* d_in, const int* in_sizes, int n_in,
                              void* d_out, int out_size, void* d_ws, size_t ws_size,
                              hipStream_t stream)
{
    const float* x     = (const float*)d_in[0];
    const int*   eidx  = (const int*)d_in[1];
    const float* attr  = (const float*)d_in[2];
    const float* W1    = (const float*)d_in[3];
    const float* root1 = (const float*)d_in[4];
    const float* b1    = (const float*)d_in[5];
    const float* W2    = (const float*)d_in[6];
    const float* root2 = (const float*)d_in[7];
    const float* b2    = (const float*)d_in[8];
    const float* Wm1   = (const float*)d_in[9];
    const float* bm1   = (const float*)d_in[10];
    const float* Wm2   = (const float*)d_in[11];
    const float* bm2   = (const float*)d_in[12];
    float* out = (float*)d_out;

    int N = in_sizes[0] / D_FEAT;
    int E = in_sizes[1] / 2;
    const int* esrc = eidx;
    const int* edst = eidx + E;

    float* agg = (float*)d_ws;
    float* h1  = agg + (size_t)N * 5 * D_FEAT;
    float* h2  = h1 + (size_t)N * D_FEAT;
    unsigned int* deg = (unsigned int*)(h2 + (size_t)N * D_FEAT);

    const int wpb = 4;                 // waves (work items) per 256-thread block
    dim3 blk(256);
    dim3 grid_e((E + wpb - 1) / wpb);
    dim3 grid_n((N + wpb - 1) / wpb);

    // ws is poisoned 0xAA before every timed call — zero what we accumulate into.
    hipMemsetAsync(deg, 0, (size_t)N * sizeof(unsigned int), stream);
    hipMemsetAsync(agg, 0, (size_t)N * 3 * D_FEAT * sizeof(float), stream);

    scatter_k<3, true><<<grid_e, blk, 0, stream>>>(x, esrc, edst, attr, agg, deg, E);
    conv_out_k<3><<<grid_n, blk, 0, stream>>>(agg, x, W1, root1, b1, deg, h1, N);

    hipMemsetAsync(agg, 0, (size_t)N * 5 * D_FEAT * sizeof(float), stream);
    scatter_k<5, false><<<grid_e, blk, 0, stream>>>(h1, esrc, edst, attr, agg, nullptr, E);
    conv_out_k<5><<<grid_n, blk, 0, stream>>>(agg, h1, W2, root2, b2, deg, h2, N);

    mlp_fused<<<grid_n, blk, 0, stream>>>(h2, Wm1, bm1, Wm2, bm2, out, N);
}

// Round 2
// 838.325 us; speedup vs baseline: 2.9418x; 2.9418x over previous
//
#include <hip/hip_runtime.h>
#include <cstdint>
#include <cstddef>

// SplineNet: 2x SplineConv (K=3, K=5) + ELU, MLP head. N=100K, E=1.6M, D=64, C=16.
//
// R2 structure: CSR-by-dst build (hist -> single-block scan -> permute), then
// per-conv: gather (wave/node, lane=feature, K reg accumulators, hat-fn coeffs,
// pre-divided by degree) -> LDS-tiled fp32 GEMM out=[agg|x]@[W;root]+b, ELU.
// GEMM reused for MLP1 (in-place); small shuffle kernel for MLP2.
//
// ws layout (bytes): agg[N*320 f] 128MB | h[N*64 f] 25.6MB | packed[E int2] 12.8MB
//                    | rowptr[N+1 u32] | cursor[N u32] | deg[N u32]  ~= 167MB.

#define D_FEAT 64

__device__ __forceinline__ float elu_f(float x) {
    return x > 0.f ? x : expm1f(x);
}

// ---------- CSR build ----------

__global__ __launch_bounds__(256) void hist_k(
    const int* __restrict__ edst, unsigned int* __restrict__ deg, int E)
{
    int e = blockIdx.x * 256 + threadIdx.x;
    if (e < E) atomicAdd(&deg[edst[e]], 1u);
}

__global__ __launch_bounds__(1024) void scan_k(
    const unsigned int* __restrict__ deg,
    unsigned int* __restrict__ rowptr,
    unsigned int* __restrict__ cursor, int N)
{
    __shared__ unsigned int wsum[16];
    __shared__ unsigned int stot;
    int lane = threadIdx.x & 63, wid = threadIdx.x >> 6;
    unsigned int run = 0;
    for (int base = 0; base < N; base += 1024) {
        int i = base + threadIdx.x;
        unsigned int v = (i < N) ? deg[i] : 0u;
        unsigned int orig = v;
        #pragma unroll
        for (int off = 1; off < 64; off <<= 1) {
            unsigned int t = __shfl_up(v, off);
            if (lane >= off) v += t;
        }
        if (lane == 63) wsum[wid] = v;
        __syncthreads();
        if (threadIdx.x < 16) {
            unsigned int wv = wsum[threadIdx.x];
            #pragma unroll
            for (int off = 1; off < 16; off <<= 1) {
                unsigned int t2 = __shfl_up(wv, off);
                if (threadIdx.x >= off) wv += t2;
            }
            wsum[threadIdx.x] = wv;
            if (threadIdx.x == 15) stot = wv;
        }
        __syncthreads();
        unsigned int boff = run + (wid ? wsum[wid - 1] : 0u);
        if (i < N) {
            unsigned int ex = boff + v - orig;
            rowptr[i] = ex;
            cursor[i] = ex;
        }
        run += stot;
        __syncthreads();   // wsum/stot reused next iter
    }
    if (threadIdx.x == 0) rowptr[N] = run;
}

__global__ __launch_bounds__(256) void permute_k(
    const int* __restrict__ esrc, const int* __restrict__ edst,
    const float* __restrict__ attr, unsigned int* __restrict__ cursor,
    int2* __restrict__ packed, int E)
{
    int e = blockIdx.x * 256 + threadIdx.x;
    if (e < E) {
        int d = edst[e];
        unsigned int pos = atomicAdd(&cursor[d], 1u);
        packed[pos] = make_int2(esrc[e], __float_as_int(attr[e]));
    }
}

// ---------- gather: agg[n][k][:] = (1/deg) * sum_e coeff_k(e) * x[src(e)][:] ----------

template<int K>
__global__ __launch_bounds__(256) void gather_k(
    const float* __restrict__ xin,
    const int2* __restrict__ packed,
    const unsigned int* __restrict__ rowptr,
    float* __restrict__ agg, int N)
{
    int n = blockIdx.x * 4 + (threadIdx.x >> 6);
    int lane = threadIdx.x & 63;
    if (n >= N) return;
    unsigned int s0 = rowptr[n], s1 = rowptr[n + 1];
    float acc[K];
    #pragma unroll
    for (int k = 0; k < K; ++k) acc[k] = 0.f;
    for (unsigned int e = s0; e < s1; ++e) {
        int2 pe = packed[e];                       // wave-broadcast load
        float v = __int_as_float(pe.y) * (float)(K - 1);
        float xv = xin[(size_t)pe.x * D_FEAT + lane];
        #pragma unroll
        for (int k = 0; k < K; ++k) {
            // degree-1 open B-spline hat: weight_k = max(0, 1-|v-k|)
            float w = fmaxf(1.f - fabsf(v - (float)k), 0.f);
            acc[k] = fmaf(xv, w, acc[k]);
        }
    }
    float inv = 1.f / fmaxf((float)(s1 - s0), 1.f);
    #pragma unroll
    for (int k = 0; k < K; ++k)
        agg[((size_t)n * K + k) * D_FEAT + lane] = acc[k] * inv;
}

// ---------- tiled GEMM: out = act( [A | X] @ [WA ; WX] + bias ) ----------
// A: [N, lenA] (ld=ldA, may be 0-length), X: [N,64], WA: [lenA][64], WX: [64][64].
// 64x64 tile per 256-thread block, 4x4 register blocking.

template<int ACT>   // 0 = ELU, 1 = ReLU
__global__ __launch_bounds__(256) void gemm_tile(
    const float* __restrict__ A, int ldA, int lenA,
    const float* __restrict__ X,
    const float* __restrict__ WA,
    const float* __restrict__ WX,
    const float* __restrict__ bias,
    float* __restrict__ out, int N)
{
    __shared__ float As[16][68];
    __shared__ float Bs[16][68];
    int t = threadIdx.x;
    int tx = t & 15, ty = t >> 4;
    int row0 = blockIdx.x * 64;
    float acc[4][4];
    #pragma unroll
    for (int i = 0; i < 4; ++i)
        #pragma unroll
        for (int j = 0; j < 4; ++j) acc[i][j] = 0.f;

    int lrow = t >> 2;            // 0..63: node-row this thread stages
    int lkq  = (t & 3) << 2;      // 0,4,8,12: k-quad
    int bkr  = t >> 4;            // 0..15: W row this thread stages
    int bcol = (t & 15) << 2;     // 0..60

    #pragma unroll
    for (int seg = 0; seg < 2; ++seg) {
        const float* Aseg = seg ? X : A;
        const float* Wseg = seg ? WX : WA;
        int len = seg ? D_FEAT : lenA;
        int ld  = seg ? D_FEAT : ldA;
        for (int kk = 0; kk < len; kk += 16) {
            int gr = row0 + lrow; if (gr >= N) gr = N - 1;
            float4 a4 = *(const float4*)(Aseg + (size_t)gr * ld + kk + lkq);
            float4 b4 = *(const float4*)(Wseg + (size_t)(kk + bkr) * D_FEAT + bcol);
            __syncthreads();
            As[lkq + 0][lrow] = a4.x;
            As[lkq + 1][lrow] = a4.y;
            As[lkq + 2][lrow] = a4.z;
            As[lkq + 3][lrow] = a4.w;
            *(float4*)(&Bs[bkr][bcol]) = b4;
            __syncthreads();
            #pragma unroll
            for (int k = 0; k < 16; ++k) {
                float4 av = *(const float4*)(&As[k][ty << 2]);
                float4 bv = *(const float4*)(&Bs[k][tx << 2]);
                acc[0][0] = fmaf(av.x, bv.x, acc[0][0]);
                acc[0][1] = fmaf(av.x, bv.y, acc[0][1]);
                acc[0][2] = fmaf(av.x, bv.z, acc[0][2]);
                acc[0][3] = fmaf(av.x, bv.w, acc[0][3]);
                acc[1][0] = fmaf(av.y, bv.x, acc[1][0]);
                acc[1][1] = fmaf(av.y, bv.y, acc[1][1]);
                acc[1][2] = fmaf(av.y, bv.z, acc[1][2]);
                acc[1][3] = fmaf(av.y, bv.w, acc[1][3]);
                acc[2][0] = fmaf(av.z, bv.x, acc[2][0]);
                acc[2][1] = fmaf(av.z, bv.y, acc[2][1]);
                acc[2][2] = fmaf(av.z, bv.z, acc[2][2]);
                acc[2][3] = fmaf(av.z, bv.w, acc[2][3]);
                acc[3][0] = fmaf(av.w, bv.x, acc[3][0]);
                acc[3][1] = fmaf(av.w, bv.y, acc[3][1]);
                acc[3][2] = fmaf(av.w, bv.z, acc[3][2]);
                acc[3][3] = fmaf(av.w, bv.w, acc[3][3]);
            }
        }
    }

    float4 bv4 = *(const float4*)(bias + (tx << 2));
    float bb[4] = {bv4.x, bv4.y, bv4.z, bv4.w};
    #pragma unroll
    for (int i = 0; i < 4; ++i) {
        int r = row0 + (ty << 2) + i;
        if (r < N) {
            float4 o;
            float vals[4];
            #pragma unroll
            for (int j = 0; j < 4; ++j) {
                float rr = acc[i][j] + bb[j];
                vals[j] = (ACT == 0) ? elu_f(rr) : fmaxf(rr, 0.f);
            }
            o.x = vals[0]; o.y = vals[1]; o.z = vals[2]; o.w = vals[3];
            *(float4*)(out + (size_t)r * D_FEAT + (tx << 2)) = o;
        }
    }
}

// ---------- MLP layer 2: out[n][c] = relu(h3[n] . Wm2[:,c] + bm2[c]) ----------

__global__ __launch_bounds__(256) void mlp2_k(
    const float* __restrict__ h3,
    const float* __restrict__ Wm2,
    const float* __restrict__ bm2,
    float* __restrict__ out, int N)
{
    int n = blockIdx.x * 4 + (threadIdx.x >> 6);
    int lane = threadIdx.x & 63;
    if (n >= N) return;
    float h = h3[(size_t)n * D_FEAT + lane];
    int c = lane & 15, part = lane >> 4;
    float p = 0.f;
    #pragma unroll
    for (int j = 0; j < 16; ++j) {
        int d = part * 16 + j;
        float hd = __shfl(h, d);
        p = fmaf(hd, Wm2[d * 16 + c], p);
    }
    p += __shfl_xor(p, 16);
    p += __shfl_xor(p, 32);
    if (lane < 16)
        out[(size_t)n * 16 + lane] = fmaxf(p + bm2[lane], 0.f);
}

extern "C" void kernel_launch(void* const* d_in, const int* in_sizes, int n_in,
                              void* d_out, int out_size, void* d_ws, size_t ws_size,
                              hipStream_t stream)
{
    const float* x     = (const float*)d_in[0];
    const int*   eidx  = (const int*)d_in[1];
    const float* attr  = (const float*)d_in[2];
    const float* W1    = (const float*)d_in[3];
    const float* root1 = (const float*)d_in[4];
    const float* b1    = (const float*)d_in[5];
    const float* W2    = (const float*)d_in[6];
    const float* root2 = (const float*)d_in[7];
    const float* b2    = (const float*)d_in[8];
    const float* Wm1   = (const float*)d_in[9];
    const float* bm1   = (const float*)d_in[10];
    const float* Wm2   = (const float*)d_in[11];
    const float* bm2   = (const float*)d_in[12];
    float* out = (float*)d_out;

    int N = in_sizes[0] / D_FEAT;
    int E = in_sizes[1] / 2;
    const int* esrc = eidx;
    const int* edst = eidx + E;

    float* agg = (float*)d_ws;
    float* h   = agg + (size_t)N * 5 * D_FEAT;
    int2*  packed = (int2*)(h + (size_t)N * D_FEAT);
    unsigned int* rowptr = (unsigned int*)(packed + E);
    unsigned int* cursor = rowptr + (N + 1);
    unsigned int* deg    = cursor + N;

    dim3 blk(256);
    dim3 grid_e((E + 255) / 256);
    dim3 grid_w((N + 3) / 4);       // wave-per-node kernels
    dim3 grid_g((N + 63) / 64);     // gemm tiles

    // CSR build (graph is identical both layers; built once per call)
    hipMemsetAsync(deg, 0, (size_t)N * sizeof(unsigned int), stream);
    hist_k<<<grid_e, blk, 0, stream>>>(edst, deg, E);
    scan_k<<<1, 1024, 0, stream>>>(deg, rowptr, cursor, N);
    permute_k<<<grid_e, blk, 0, stream>>>(esrc, edst, attr, cursor, packed, E);

    // conv1: K=3
    gather_k<3><<<grid_w, blk, 0, stream>>>(x, packed, rowptr, agg, N);
    gemm_tile<0><<<grid_g, blk, 0, stream>>>(agg, 3 * D_FEAT, 3 * D_FEAT, x, W1, root1, b1, h, N);

    // conv2: K=5  (reads h, writes h in place — safe: per-block row ownership)
    gather_k<5><<<grid_w, blk, 0, stream>>>(h, packed, rowptr, agg, N);
    gemm_tile<0><<<grid_g, blk, 0, stream>>>(agg, 5 * D_FEAT, 5 * D_FEAT, h, W2, root2, b2, h, N);

    // MLP1 (in place), MLP2
    gemm_tile<1><<<grid_g, blk, 0, stream>>>(nullptr, 0, 0, h, nullptr, Wm1, bm1, h, N);
    mlp2_k<<<grid_w, blk, 0, stream>>>(h, Wm2, bm2, out, N);
}

// Round 3
// 609.625 us; speedup vs baseline: 4.0455x; 1.3751x over previous
//
#include <hip/hip_runtime.h>
#include <cstdint>
#include <cstddef>

// SplineNet: 2x SplineConv (K=3, K=5) + ELU, MLP head. N=100K, E=1.6M, D=64, C=16.
//
// R3: gather processes 4 edges/wave with float4 lanes (4 gathers in flight);
// multi-block scan; MLP1+MLP2 fused in one tile kernel (LDS round-trip).
//
// ws layout (floats): agg[N*320] | h[N*64] | packed[E int2] | rowptr[N+1] |
//                     cursor[N] | deg[N] | partial[512]   ~= 168 MB.

#define D_FEAT 64

__device__ __forceinline__ float elu_f(float x) {
    return x > 0.f ? x : expm1f(x);
}

// ---------- CSR build ----------

__global__ __launch_bounds__(256) void hist_k(
    const int* __restrict__ edst, unsigned int* __restrict__ deg, int E)
{
    int e = blockIdx.x * 256 + threadIdx.x;
    if (e < E) atomicAdd(&deg[edst[e]], 1u);
}

// pass 1: per-block (256-wide) sums of deg
__global__ __launch_bounds__(256) void part_sum_k(
    const unsigned int* __restrict__ deg, unsigned int* __restrict__ partial, int N)
{
    __shared__ unsigned int wsum[4];
    int i = blockIdx.x * 256 + threadIdx.x;
    int lane = threadIdx.x & 63, wid = threadIdx.x >> 6;
    unsigned int v = (i < N) ? deg[i] : 0u;
    #pragma unroll
    for (int off = 32; off; off >>= 1) v += __shfl_xor(v, off);
    if (lane == 0) wsum[wid] = v;
    __syncthreads();
    if (threadIdx.x == 0)
        partial[blockIdx.x] = wsum[0] + wsum[1] + wsum[2] + wsum[3];
}

// pass 2: single block, in-place exclusive scan of partial[nb] (nb <= 512)
__global__ __launch_bounds__(512) void part_scan_k(
    unsigned int* __restrict__ partial, int nb)
{
    __shared__ unsigned int wsum[8];
    int t = threadIdx.x, lane = t & 63, wid = t >> 6;
    unsigned int v = (t < nb) ? partial[t] : 0u;
    unsigned int orig = v;
    #pragma unroll
    for (int off = 1; off < 64; off <<= 1) {
        unsigned int s = __shfl_up(v, off);
        if (lane >= off) v += s;
    }
    if (lane == 63) wsum[wid] = v;
    __syncthreads();
    unsigned int add = 0;
    for (int i = 0; i < wid; ++i) add += wsum[i];
    if (t < nb) partial[t] = v + add - orig;
}

// pass 3: per-block exclusive scan + block offset; write rowptr & cursor
__global__ __launch_bounds__(256) void scan_write_k(
    const unsigned int* __restrict__ deg, const unsigned int* __restrict__ partial,
    unsigned int* __restrict__ rowptr, unsigned int* __restrict__ cursor, int N, int E)
{
    __shared__ unsigned int wsum[4];
    int i = blockIdx.x * 256 + threadIdx.x;
    int lane = threadIdx.x & 63, wid = threadIdx.x >> 6;
    unsigned int v = (i < N) ? deg[i] : 0u;
    unsigned int orig = v;
    #pragma unroll
    for (int off = 1; off < 64; off <<= 1) {
        unsigned int s = __shfl_up(v, off);
        if (lane >= off) v += s;
    }
    if (lane == 63) wsum[wid] = v;
    __syncthreads();
    unsigned int add = partial[blockIdx.x];
    for (int w = 0; w < wid; ++w) add += wsum[w];
    unsigned int excl = add + v - orig;
    if (i < N) { rowptr[i] = excl; cursor[i] = excl; }
    if (blockIdx.x == 0 && threadIdx.x == 0) rowptr[N] = (unsigned int)E;
}

__global__ __launch_bounds__(256) void permute_k(
    const int* __restrict__ esrc, const int* __restrict__ edst,
    const float* __restrict__ attr, unsigned int* __restrict__ cursor,
    int2* __restrict__ packed, int E)
{
    int e = blockIdx.x * 256 + threadIdx.x;
    if (e < E) {
        int d = edst[e];
        unsigned int pos = atomicAdd(&cursor[d], 1u);
        packed[pos] = make_int2(esrc[e], __float_as_int(attr[e]));
    }
}

// ---------- gather: agg[n][k][:] = (1/deg) * sum_e coeff_k(e) * x[src(e)][:]
// wave = one node; lane = (edge-slot sub 0..3) x (16 float4 columns).
// 4 edges in flight per iteration; cross-sub shuffle reduce at the end.

template<int K>
__global__ __launch_bounds__(256) void gather_k(
    const float* __restrict__ xin,
    const int2* __restrict__ packed,
    const unsigned int* __restrict__ rowptr,
    float* __restrict__ agg, int N)
{
    int n = blockIdx.x * 4 + (threadIdx.x >> 6);
    int lane = threadIdx.x & 63;
    if (n >= N) return;
    int sub = lane >> 4;
    int col = (lane & 15) << 2;
    unsigned int s0 = rowptr[n], s1 = rowptr[n + 1];
    float4 acc[K];
    #pragma unroll
    for (int k = 0; k < K; ++k) acc[k] = make_float4(0.f, 0.f, 0.f, 0.f);
    for (unsigned int e = s0; e < s1; e += 4) {
        unsigned int ee = e + (unsigned int)sub;
        bool valid = ee < s1;
        int2 pe = packed[valid ? ee : s1 - 1];
        float v = __int_as_float(pe.y) * (float)(K - 1);
        const float4 xv = *(const float4*)(xin + (size_t)pe.x * D_FEAT + col);
        #pragma unroll
        for (int k = 0; k < K; ++k) {
            // degree-1 open B-spline hat: weight_k = max(0, 1-|v-k|)
            float w = fmaxf(1.f - fabsf(v - (float)k), 0.f);
            w = valid ? w : 0.f;
            acc[k].x = fmaf(xv.x, w, acc[k].x);
            acc[k].y = fmaf(xv.y, w, acc[k].y);
            acc[k].z = fmaf(xv.z, w, acc[k].z);
            acc[k].w = fmaf(xv.w, w, acc[k].w);
        }
    }
    float inv = 1.f / fmaxf((float)(s1 - s0), 1.f);
    #pragma unroll
    for (int k = 0; k < K; ++k) {
        float4 a = acc[k];
        a.x += __shfl_xor(a.x, 16); a.x += __shfl_xor(a.x, 32);
        a.y += __shfl_xor(a.y, 16); a.y += __shfl_xor(a.y, 32);
        a.z += __shfl_xor(a.z, 16); a.z += __shfl_xor(a.z, 32);
        a.w += __shfl_xor(a.w, 16); a.w += __shfl_xor(a.w, 32);
        if (sub == 0) {
            a.x *= inv; a.y *= inv; a.z *= inv; a.w *= inv;
            *(float4*)(agg + ((size_t)n * K + k) * D_FEAT + col) = a;
        }
    }
}

// ---------- tiled GEMM: out = elu( [A | X] @ [WA ; WX] + bias ) ----------

__global__ __launch_bounds__(256) void gemm_tile(
    const float* __restrict__ A, int lenA,
    const float* __restrict__ X,
    const float* __restrict__ WA,
    const float* __restrict__ WX,
    const float* __restrict__ bias,
    float* __restrict__ out, int N)
{
    __shared__ float As[16][68];
    __shared__ float Bs[16][68];
    int t = threadIdx.x;
    int tx = t & 15, ty = t >> 4;
    int row0 = blockIdx.x * 64;
    float acc[4][4];
    #pragma unroll
    for (int i = 0; i < 4; ++i)
        #pragma unroll
        for (int j = 0; j < 4; ++j) acc[i][j] = 0.f;

    int lrow = t >> 2;
    int lkq  = (t & 3) << 2;
    int bkr  = t >> 4;
    int bcol = (t & 15) << 2;

    #pragma unroll
    for (int seg = 0; seg < 2; ++seg) {
        const float* Aseg = seg ? X : A;
        const float* Wseg = seg ? WX : WA;
        int len = seg ? D_FEAT : lenA;
        for (int kk = 0; kk < len; kk += 16) {
            int gr = row0 + lrow; if (gr >= N) gr = N - 1;
            float4 a4 = *(const float4*)(Aseg + (size_t)gr * len + kk + lkq);
            float4 b4 = *(const float4*)(Wseg + (size_t)(kk + bkr) * D_FEAT + bcol);
            __syncthreads();
            As[lkq + 0][lrow] = a4.x;
            As[lkq + 1][lrow] = a4.y;
            As[lkq + 2][lrow] = a4.z;
            As[lkq + 3][lrow] = a4.w;
            *(float4*)(&Bs[bkr][bcol]) = b4;
            __syncthreads();
            #pragma unroll
            for (int k = 0; k < 16; ++k) {
                float4 av = *(const float4*)(&As[k][ty << 2]);
                float4 bv = *(const float4*)(&Bs[k][tx << 2]);
                acc[0][0] = fmaf(av.x, bv.x, acc[0][0]);
                acc[0][1] = fmaf(av.x, bv.y, acc[0][1]);
                acc[0][2] = fmaf(av.x, bv.z, acc[0][2]);
                acc[0][3] = fmaf(av.x, bv.w, acc[0][3]);
                acc[1][0] = fmaf(av.y, bv.x, acc[1][0]);
                acc[1][1] = fmaf(av.y, bv.y, acc[1][1]);
                acc[1][2] = fmaf(av.y, bv.z, acc[1][2]);
                acc[1][3] = fmaf(av.y, bv.w, acc[1][3]);
                acc[2][0] = fmaf(av.z, bv.x, acc[2][0]);
                acc[2][1] = fmaf(av.z, bv.y, acc[2][1]);
                acc[2][2] = fmaf(av.z, bv.z, acc[2][2]);
                acc[2][3] = fmaf(av.z, bv.w, acc[2][3]);
                acc[3][0] = fmaf(av.w, bv.x, acc[3][0]);
                acc[3][1] = fmaf(av.w, bv.y, acc[3][1]);
                acc[3][2] = fmaf(av.w, bv.z, acc[3][2]);
                acc[3][3] = fmaf(av.w, bv.w, acc[3][3]);
            }
        }
    }

    float4 bv4 = *(const float4*)(bias + (tx << 2));
    float bb[4] = {bv4.x, bv4.y, bv4.z, bv4.w};
    #pragma unroll
    for (int i = 0; i < 4; ++i) {
        int r = row0 + (ty << 2) + i;
        if (r < N) {
            float4 o;
            o.x = elu_f(acc[i][0] + bb[0]);
            o.y = elu_f(acc[i][1] + bb[1]);
            o.z = elu_f(acc[i][2] + bb[2]);
            o.w = elu_f(acc[i][3] + bb[3]);
            *(float4*)(out + (size_t)r * D_FEAT + (tx << 2)) = o;
        }
    }
}

// ---------- fused MLP: out = relu( relu(h@Wm1+bm1) @ Wm2 + bm2 ) ----------
// Same 64x64 tiling for layer 1; hidden tile round-trips through LDS; then a
// 64x16 mini-GEMM (thread = row x 4-col group) writes the output tile.

__global__ __launch_bounds__(256) void mlp_tile(
    const float* __restrict__ X,      // h [N,64]
    const float* __restrict__ Wm1,    // [64][64]
    const float* __restrict__ bm1,    // [64]
    const float* __restrict__ Wm2,    // [64][16]
    const float* __restrict__ bm2,    // [16]
    float* __restrict__ out, int N)
{
    __shared__ float As[16][68];
    __shared__ float Bs[16][68];
    __shared__ float Hs[64][68];
    int t = threadIdx.x;
    int tx = t & 15, ty = t >> 4;
    int row0 = blockIdx.x * 64;
    float acc[4][4];
    #pragma unroll
    for (int i = 0; i < 4; ++i)
        #pragma unroll
        for (int j = 0; j < 4; ++j) acc[i][j] = 0.f;

    int lrow = t >> 2;
    int lkq  = (t & 3) << 2;
    int bkr  = t >> 4;
    int bcol = (t & 15) << 2;

    for (int kk = 0; kk < D_FEAT; kk += 16) {
        int gr = row0 + lrow; if (gr >= N) gr = N - 1;
        float4 a4 = *(const float4*)(X + (size_t)gr * D_FEAT + kk + lkq);
        float4 b4 = *(const float4*)(Wm1 + (size_t)(kk + bkr) * D_FEAT + bcol);
        __syncthreads();
        As[lkq + 0][lrow] = a4.x;
        As[lkq + 1][lrow] = a4.y;
        As[lkq + 2][lrow] = a4.z;
        As[lkq + 3][lrow] = a4.w;
        *(float4*)(&Bs[bkr][bcol]) = b4;
        __syncthreads();
        #pragma unroll
        for (int k = 0; k < 16; ++k) {
            float4 av = *(const float4*)(&As[k][ty << 2]);
            float4 bv = *(const float4*)(&Bs[k][tx << 2]);
            acc[0][0] = fmaf(av.x, bv.x, acc[0][0]);
            acc[0][1] = fmaf(av.x, bv.y, acc[0][1]);
            acc[0][2] = fmaf(av.x, bv.z, acc[0][2]);
            acc[0][3] = fmaf(av.x, bv.w, acc[0][3]);
            acc[1][0] = fmaf(av.y, bv.x, acc[1][0]);
            acc[1][1] = fmaf(av.y, bv.y, acc[1][1]);
            acc[1][2] = fmaf(av.y, bv.z, acc[1][2]);
            acc[1][3] = fmaf(av.y, bv.w, acc[1][3]);
            acc[2][0] = fmaf(av.z, bv.x, acc[2][0]);
            acc[2][1] = fmaf(av.z, bv.y, acc[2][1]);
            acc[2][2] = fmaf(av.z, bv.z, acc[2][2]);
            acc[2][3] = fmaf(av.z, bv.w, acc[2][3]);
            acc[3][0] = fmaf(av.w, bv.x, acc[3][0]);
            acc[3][1] = fmaf(av.w, bv.y, acc[3][1]);
            acc[3][2] = fmaf(av.w, bv.z, acc[3][2]);
            acc[3][3] = fmaf(av.w, bv.w, acc[3][3]);
        }
    }

    float4 bv4 = *(const float4*)(bm1 + (tx << 2));
    #pragma unroll
    for (int i = 0; i < 4; ++i) {
        float4 o;
        o.x = fmaxf(acc[i][0] + bv4.x, 0.f);
        o.y = fmaxf(acc[i][1] + bv4.y, 0.f);
        o.z = fmaxf(acc[i][2] + bv4.z, 0.f);
        o.w = fmaxf(acc[i][3] + bv4.w, 0.f);
        *(float4*)(&Hs[(ty << 2) + i][tx << 2]) = o;
    }
    __syncthreads();

    // layer 2: thread t -> row r = t>>2, cols cg..cg+3
    int r = t >> 2;
    int cg = (t & 3) << 2;
    float4 o2 = make_float4(0.f, 0.f, 0.f, 0.f);
    #pragma unroll 8
    for (int k = 0; k < D_FEAT; ++k) {
        float hk = Hs[k == 0 ? r : r][k];   // broadcast within 4-thread groups
        float4 w4 = *(const float4*)(Wm2 + k * 16 + cg);
        o2.x = fmaf(hk, w4.x, o2.x);
        o2.y = fmaf(hk, w4.y, o2.y);
        o2.z = fmaf(hk, w4.z, o2.z);
        o2.w = fmaf(hk, w4.w, o2.w);
    }
    int gr = row0 + r;
    if (gr < N) {
        float4 b2 = *(const float4*)(bm2 + cg);
        float4 o;
        o.x = fmaxf(o2.x + b2.x, 0.f);
        o.y = fmaxf(o2.y + b2.y, 0.f);
        o.z = fmaxf(o2.z + b2.z, 0.f);
        o.w = fmaxf(o2.w + b2.w, 0.f);
        *(float4*)(out + (size_t)gr * 16 + cg) = o;
    }
}

extern "C" void kernel_launch(void* const* d_in, const int* in_sizes, int n_in,
                              void* d_out, int out_size, void* d_ws, size_t ws_size,
                              hipStream_t stream)
{
    const float* x     = (const float*)d_in[0];
    const int*   eidx  = (const int*)d_in[1];
    const float* attr  = (const float*)d_in[2];
    const float* W1    = (const float*)d_in[3];
    const float* root1 = (const float*)d_in[4];
    const float* b1    = (const float*)d_in[5];
    const float* W2    = (const float*)d_in[6];
    const float* root2 = (const float*)d_in[7];
    const float* b2    = (const float*)d_in[8];
    const float* Wm1   = (const float*)d_in[9];
    const float* bm1   = (const float*)d_in[10];
    const float* Wm2   = (const float*)d_in[11];
    const float* bm2   = (const float*)d_in[12];
    float* out = (float*)d_out;

    int N = in_sizes[0] / D_FEAT;
    int E = in_sizes[1] / 2;
    const int* esrc = eidx;
    const int* edst = eidx + E;

    float* agg = (float*)d_ws;
    float* h   = agg + (size_t)N * 5 * D_FEAT;
    int2*  packed = (int2*)(h + (size_t)N * D_FEAT);
    unsigned int* rowptr  = (unsigned int*)(packed + E);
    unsigned int* cursor  = rowptr + (N + 1);
    unsigned int* deg     = cursor + N;
    unsigned int* partial = deg + N;

    dim3 blk(256);
    int nb = (N + 255) / 256;
    dim3 grid_e((E + 255) / 256);
    dim3 grid_s(nb);
    dim3 grid_w((N + 3) / 4);
    dim3 grid_g((N + 63) / 64);

    // CSR build
    hipMemsetAsync(deg, 0, (size_t)N * sizeof(unsigned int), stream);
    hist_k<<<grid_e, blk, 0, stream>>>(edst, deg, E);
    part_sum_k<<<grid_s, blk, 0, stream>>>(deg, partial, N);
    part_scan_k<<<1, 512, 0, stream>>>(partial, nb);
    scan_write_k<<<grid_s, blk, 0, stream>>>(deg, partial, rowptr, cursor, N, E);
    permute_k<<<grid_e, blk, 0, stream>>>(esrc, edst, attr, cursor, packed, E);

    // conv1: K=3
    gather_k<3><<<grid_w, blk, 0, stream>>>(x, packed, rowptr, agg, N);
    gemm_tile<<<grid_g, blk, 0, stream>>>(agg, 3 * D_FEAT, x, W1, root1, b1, h, N);

    // conv2: K=5 (reads h, writes h in place — per-block row ownership)
    gather_k<5><<<grid_w, blk, 0, stream>>>(h, packed, rowptr, agg, N);
    gemm_tile<<<grid_g, blk, 0, stream>>>(agg, 5 * D_FEAT, h, W2, root2, b2, h, N);

    // fused MLP head
    mlp_tile<<<grid_g, blk, 0, stream>>>(h, Wm1, bm1, Wm2, bm2, out, N);
}